// Round 6
// baseline (99.540 us; speedup 1.0000x reference)
//
#include <hip/hip_runtime.h>
#include <math.h>

// GP_conv2D: N=8, IH=IW=32, IC=8, OC=16, 3x3 s1 p1, P=5, I_DIM=72
#define OC_N   16
#define I_DIM  72
#define PN     5
#define NEU    (OC_N * I_DIM)   // 1152
#define NF     32               // floats per neuron record (128 B)
#define RTOT   8192             // N * OH * OW
#define OUT_HALF (RTOT * OC_N)  // 131072
#define LOG2E  1.4426950408889634f
#define RLOG2E 0.6931471805599453f

#if __has_builtin(__builtin_amdgcn_rcpf)
#define RCPF(x) __builtin_amdgcn_rcpf(x)
#else
#define RCPF(x) (1.0f / (x))
#endif
#if __has_builtin(__builtin_amdgcn_exp2f)
#define EXP2F(x) __builtin_amdgcn_exp2f(x)
#else
#define EXP2F(x) exp2f(x)
#endif
#if __has_builtin(__builtin_amdgcn_logf)
#define LOG2F(x) __builtin_amdgcn_logf(x)
#else
#define LOG2F(x) log2f(x)
#endif

// Neuron record layout (32 floats):
// [0]=l2  [1]=pad  [2..6]=z[p]  [7..11]=alpha[p]
// [12..16]=Kinv diag  [17..26]=2*Kinv offdiag (01,02,03,04,12,13,14,23,24,34)

__global__ __launch_bounds__(256) void gp_prep_kernel(
    const float* __restrict__ zin, const float* __restrict__ hin,
    const float* __restrict__ rlin, float* __restrict__ nr) {
  int idx = blockIdx.x * blockDim.x + threadIdx.x;
  if (idx >= NEU) return;
  // softplus via native exp2/log2: log1p(e^x) = max(x,0) + ln(1 + e^-|x|)
  float x  = rlin[idx];
  float t  = EXP2F(-fabsf(x) * LOG2E);
  float sp = fmaxf(x, 0.0f) + LOG2F(1.0f + t) * RLOG2E;
  float l2 = sp * sp;
  float cexp = -0.5f * LOG2E * RCPF(l2);          // exponent scale for K

  float zz[PN], hh[PN];
#pragma unroll
  for (int p = 0; p < PN; ++p) {
    zz[p] = zin[idx * PN + p];
    hh[p] = hin[idx * PN + p];
  }
  float A[PN][PN], B[PN][PN];
#pragma unroll
  for (int p = 0; p < PN; ++p) {
#pragma unroll
    for (int q = 0; q < PN; ++q) {
      float dz = zz[p] - zz[q];
      A[p][q] = EXP2F(cexp * dz * dz);            // native v_exp_f32
      B[p][q] = (p == q) ? 1.0f : 0.0f;
    }
  }
#pragma unroll
  for (int p = 0; p < PN; ++p) A[p][p] += 1e-4f;  // jitter

  // Gauss-Jordan inverse (SPD + jitter -> no pivoting), fp32, native rcp
#pragma unroll
  for (int c = 0; c < PN; ++c) {
    float pivinv = RCPF(A[c][c]);
#pragma unroll
    for (int j = 0; j < PN; ++j) { A[c][j] *= pivinv; B[c][j] *= pivinv; }
#pragma unroll
    for (int r = 0; r < PN; ++r) {
      if (r == c) continue;
      float f = A[r][c];
#pragma unroll
      for (int j = 0; j < PN; ++j) { A[r][j] -= f * A[c][j]; B[r][j] -= f * B[c][j]; }
    }
  }
  float alpha[PN];
#pragma unroll
  for (int p = 0; p < PN; ++p) {
    float s = 0.0f;
#pragma unroll
    for (int q = 0; q < PN; ++q) s += B[p][q] * hh[q];
    alpha[p] = s;
  }
  float* o = nr + idx * NF;
  o[0] = l2;
  o[1] = 0.0f;
#pragma unroll
  for (int p = 0; p < PN; ++p) {
    o[2 + p]  = zz[p];
    o[7 + p]  = alpha[p];
    o[12 + p] = B[p][p];
  }
  int j = 17;
#pragma unroll
  for (int p = 0; p < PN; ++p)
#pragma unroll
    for (int q = p + 1; q < PN; ++q) o[j++] = 2.0f * B[p][q];
  o[27] = o[28] = o[29] = o[30] = o[31] = 0.0f;
}

// Fused main, VGPR-resident params.
// Block = 9 waves (tap k = threadIdx.y). Lane = (rlo = lane>>3, c = lane&7).
// Each wave loads its (o, c(lane), k) neuron record ONCE into 27 VGPRs,
// then iterates 8 row-octets: one coalesced 256B load each for mu and s2,
// per-lane GP math, shfl_xor c-reduction, masked LDS write. One barrier,
// wave 0 folds the 9 tap-partials and stores.
__global__ __launch_bounds__(576) void gp_fused_kernel(
    const float* __restrict__ xm, const float* __restrict__ xv,
    const float* __restrict__ nr, float* __restrict__ out) {
  const int tx  = threadIdx.x;                 // 0..63
  const int rlo = tx >> 3;                     // row within octet
  const int c   = tx & 7;                      // input channel
  const int k   = __builtin_amdgcn_readfirstlane(threadIdx.y);  // tap 0..8
  const int kh  = k / 3;
  const int kw  = k - kh * 3;
  const int o   = blockIdx.y;
  const int rbase = blockIdx.x * 64;           // 64 rows per block

  // ---- per-lane param preamble (loaded once, VGPR-resident) ----
  const float* rec = nr + (o * I_DIM + (c * 9 + k)) * NF;
  float P[27];
#pragma unroll
  for (int j = 0; j < 27; ++j) P[j] = rec[j];

  const float l2    = P[0];
  __shared__ float2 red[9][64];

#pragma unroll
  for (int it = 0; it < 8; ++it) {
    const int r8  = rbase + it * 8;            // first row of octet (uniform)
    const int n   = r8 >> 10;
    const int pix = r8 & 1023;
    const int oh  = pix >> 5;
    const int ow0 = pix & 31;                  // multiple of 8
    const int ih  = oh + kh - 1;               // uniform per wave-iter
    const int iw  = ow0 + rlo + kw - 1;        // per-lane
    const bool valid = ((unsigned)ih < 32u) & ((unsigned)iw < 32u);
    // clamped address (always in-bounds), zero out invalid lanes after load
    const int ihc = ih < 0 ? 0 : (ih > 31 ? 31 : ih);
    const int iwc = iw < 0 ? 0 : (iw > 31 ? 31 : iw);
    const int addr = ((n * 32 + ihc) * 32 + iwc) * 8 + c;  // coalesced per wave
    float m  = xm[addr];
    float s2 = xv[addr];
    m  = valid ? m  : 0.0f;
    s2 = valid ? s2 : 0.0f;

    const float d     = l2 + s2;
    const float inv_d = RCPF(d);
    const float coef2 = l2 * inv_d;             // == l2/d == coef^2
    const float coef  = sqrtf(coef2);
    const float el    = -0.72134752044f * inv_d; // -0.5*log2(e)/d
    const float d0 = m - P[2];
    const float d1 = m - P[3];
    const float d2 = m - P[4];
    const float d3 = m - P[5];
    const float d4 = m - P[6];
    const float u0 = EXP2F(el * d0 * d0);
    const float u1 = EXP2F(el * d1 * d1);
    const float u2 = EXP2F(el * d2 * d2);
    const float u3 = EXP2F(el * d3 * d3);
    const float u4 = EXP2F(el * d4 * d4);
    const float dotA =
        fmaf(u0, P[7], fmaf(u1, P[8], fmaf(u2, P[9], fmaf(u3, P[10], u4 * P[11]))));
    const float t0 = fmaf(P[12], u0, fmaf(P[17], u1, fmaf(P[18], u2, fmaf(P[19], u3, P[20] * u4))));
    const float t1 = fmaf(P[13], u1, fmaf(P[21], u2, fmaf(P[22], u3, P[23] * u4)));
    const float t2 = fmaf(P[14], u2, fmaf(P[24], u3, P[25] * u4));
    const float t3 = fmaf(P[15], u3, P[26] * u4);
    const float t4 = P[16] * u4;
    const float quad =
        fmaf(u0, t0, fmaf(u1, t1, fmaf(u2, t2, fmaf(u3, t3, u4 * t4))));
    float mean = coef * dotA;
    float qkq  = coef2 * quad;

    // reduce over c (low 3 lane bits): butterfly
    mean += __shfl_xor(mean, 1); qkq += __shfl_xor(qkq, 1);
    mean += __shfl_xor(mean, 2); qkq += __shfl_xor(qkq, 2);
    mean += __shfl_xor(mean, 4); qkq += __shfl_xor(qkq, 4);
    if (c == 0) red[k][it * 8 + rlo] = make_float2(mean, qkq);
  }

  __syncthreads();
  if (threadIdx.y == 0) {
    float msum = 0.0f, qsum = 0.0f;
#pragma unroll
    for (int s = 0; s < 9; ++s) {
      const float2 v = red[s][tx];
      msum += v.x;
      qsum += v.y;
    }
    const int i = (rbase + tx) * OC_N + o;
    out[i] = msum;
    out[OUT_HALF + i] = fmaxf(72.0f - qsum, 1e-6f);
  }
}

extern "C" void kernel_launch(void* const* d_in, const int* in_sizes, int n_in,
                              void* d_out, int out_size, void* d_ws, size_t ws_size,
                              hipStream_t stream) {
  const float* xm = (const float*)d_in[0];   // x_mean [8,32,32,8]
  const float* xv = (const float*)d_in[1];   // x_var  [8,32,32,8]
  const float* z  = (const float*)d_in[2];   // [16,72,5]
  const float* h  = (const float*)d_in[3];   // [16,72,5]
  const float* rl = (const float*)d_in[4];   // [16,72]
  float* out = (float*)d_out;                // mean(131072) ++ var(131072)
  float* nr  = (float*)d_ws;                 // 147456 B

  gp_prep_kernel<<<dim3((NEU + 255) / 256), dim3(256), 0, stream>>>(z, h, rl, nr);

  dim3 grid(RTOT / 64, OC_N);                // (128, 16) = 2048 blocks
  dim3 block(64, 9);                         // 576 threads = 9 waves
  gp_fused_kernel<<<grid, block, 0, stream>>>(xm, xv, nr, out);
}

// Round 7
// 94.914 us; speedup vs baseline: 1.0487x; 1.0487x over previous
//
#include <hip/hip_runtime.h>
#include <math.h>

// GP_conv2D: N=8, IH=IW=32, IC=8, OC=16, 3x3 s1 p1, P=5, I_DIM=72
#define OC_N   16
#define I_DIM  72
#define PN     5
#define NEU    (OC_N * I_DIM)   // 1152
#define NF     32               // floats per neuron record (128 B)
#define RTOT   8192             // N * OH * OW
#define OUT_HALF (RTOT * OC_N)  // 131072
#define LOG2E  1.4426950408889634f
#define RLOG2E 0.6931471805599453f

#if __has_builtin(__builtin_amdgcn_rcpf)
#define RCPF(x) __builtin_amdgcn_rcpf(x)
#else
#define RCPF(x) (1.0f / (x))
#endif
#if __has_builtin(__builtin_amdgcn_exp2f)
#define EXP2F(x) __builtin_amdgcn_exp2f(x)
#else
#define EXP2F(x) exp2f(x)
#endif
#if __has_builtin(__builtin_amdgcn_logf)
#define LOG2F(x) __builtin_amdgcn_logf(x)
#else
#define LOG2F(x) log2f(x)
#endif

// Neuron record layout (32 floats):
// [0]=l2  [1]=pad  [2..6]=z[p]  [7..11]=alpha[p]
// [12..16]=Kinv diag  [17..26]=2*Kinv offdiag (01,02,03,04,12,13,14,23,24,34)

__global__ __launch_bounds__(256) void gp_prep_kernel(
    const float* __restrict__ zin, const float* __restrict__ hin,
    const float* __restrict__ rlin, float* __restrict__ nr) {
  int idx = blockIdx.x * blockDim.x + threadIdx.x;
  if (idx >= NEU) return;
  float x  = rlin[idx];
  float t  = EXP2F(-fabsf(x) * LOG2E);
  float sp = fmaxf(x, 0.0f) + LOG2F(1.0f + t) * RLOG2E;
  float l2 = sp * sp;
  float cexp = -0.5f * LOG2E * RCPF(l2);

  float zz[PN], hh[PN];
#pragma unroll
  for (int p = 0; p < PN; ++p) {
    zz[p] = zin[idx * PN + p];
    hh[p] = hin[idx * PN + p];
  }
  float A[PN][PN], B[PN][PN];
#pragma unroll
  for (int p = 0; p < PN; ++p) {
#pragma unroll
    for (int q = 0; q < PN; ++q) {
      float dz = zz[p] - zz[q];
      A[p][q] = EXP2F(cexp * dz * dz);
      B[p][q] = (p == q) ? 1.0f : 0.0f;
    }
  }
#pragma unroll
  for (int p = 0; p < PN; ++p) A[p][p] += 1e-4f;

#pragma unroll
  for (int c = 0; c < PN; ++c) {
    float pivinv = RCPF(A[c][c]);
#pragma unroll
    for (int j = 0; j < PN; ++j) { A[c][j] *= pivinv; B[c][j] *= pivinv; }
#pragma unroll
    for (int r = 0; r < PN; ++r) {
      if (r == c) continue;
      float f = A[r][c];
#pragma unroll
      for (int j = 0; j < PN; ++j) { A[r][j] -= f * A[c][j]; B[r][j] -= f * B[c][j]; }
    }
  }
  float alpha[PN];
#pragma unroll
  for (int p = 0; p < PN; ++p) {
    float s = 0.0f;
#pragma unroll
    for (int q = 0; q < PN; ++q) s += B[p][q] * hh[q];
    alpha[p] = s;
  }
  float* o = nr + idx * NF;
  o[0] = l2;
  o[1] = 0.0f;
#pragma unroll
  for (int p = 0; p < PN; ++p) {
    o[2 + p]  = zz[p];
    o[7 + p]  = alpha[p];
    o[12 + p] = B[p][p];
  }
  int j = 17;
#pragma unroll
  for (int p = 0; p < PN; ++p)
#pragma unroll
    for (int q = p + 1; q < PN; ++q) o[j++] = 2.0f * B[p][q];
  o[27] = o[28] = o[29] = o[30] = o[31] = 0.0f;
}

// Main: 1-wave blocks, VGPR-resident params, 2 rows/lane (paired math).
// grid = (64 row-chunks of 128, OC, 9 taps). lane = (rh = lane>>3, c = lane&7).
// Wave-iter = 16 consecutive rows: lane handles rows r0+rh and r0+rh+8.
__global__ __launch_bounds__(64, 4) void gp_main_kernel(
    const float* __restrict__ xm, const float* __restrict__ xv,
    const float* __restrict__ nr, float2* __restrict__ pmq) {
  const int lane = threadIdx.x;
  const int rh = lane >> 3;                    // 0..7
  const int c  = lane & 7;
  const int k  = blockIdx.z;                   // tap 0..8 (uniform)
  const int kh = k / 3;
  const int kw = k - kh * 3;
  const int o  = blockIdx.y;
  const int rbase = blockIdx.x * 128;          // 128 rows per block
  const int n = rbase >> 10;                   // uniform (128 | 1024)
  const int ohb = (rbase & 1023) >> 5;         // first oh of chunk

  // ---- params resident in VGPRs for the whole kernel ----
  const float* rec = nr + (o * I_DIM + (c * 9 + k)) * NF;
  float P[27];
#pragma unroll
  for (int j = 0; j < 27; ++j) P[j] = rec[j];
  const float l2 = P[0];

  float2 outm[8], outq[8];                     // per-iter results (c==0 lanes)

#pragma unroll
  for (int it = 0; it < 8; ++it) {
    const int oh  = ohb + (it >> 1);
    const int ow0 = (it & 1) << 4;             // 0 or 16
    const int ih  = oh + kh - 1;               // uniform
    const int iwa = ow0 + rh + kw - 1;         // per-lane, row a
    const int iwb = iwa + 8;                   // row b
    const bool va = ((unsigned)ih < 32u) & ((unsigned)iwa < 32u);
    const bool vb = ((unsigned)ih < 32u) & ((unsigned)iwb < 32u);
    const int ihc  = ih  < 0 ? 0 : (ih  > 31 ? 31 : ih);
    const int iwac = iwa < 0 ? 0 : (iwa > 31 ? 31 : iwa);
    const int iwbc = iwb < 0 ? 0 : (iwb > 31 ? 31 : iwb);
    const int rowb = ((n * 32 + ihc) * 32) * 8 + c;
    float ma  = xm[rowb + iwac * 8];
    float mb  = xm[rowb + iwbc * 8];
    float sa  = xv[rowb + iwac * 8];
    float sb  = xv[rowb + iwbc * 8];
    ma = va ? ma : 0.0f;  sa = va ? sa : 0.0f;
    mb = vb ? mb : 0.0f;  sb = vb ? sb : 0.0f;

    const float da  = l2 + sa,            db  = l2 + sb;
    const float ia  = RCPF(da),           ib  = RCPF(db);
    const float c2a = l2 * ia,            c2b = l2 * ib;
    const float ca  = sqrtf(c2a),         cb  = sqrtf(c2b);
    const float ea  = -0.72134752044f * ia, eb = -0.72134752044f * ib;

    float ua0, ua1, ua2, ua3, ua4, ub0, ub1, ub2, ub3, ub4;
    {
      const float x0 = ma - P[2], y0 = mb - P[2];
      const float x1 = ma - P[3], y1 = mb - P[3];
      const float x2 = ma - P[4], y2 = mb - P[4];
      const float x3 = ma - P[5], y3 = mb - P[5];
      const float x4 = ma - P[6], y4 = mb - P[6];
      ua0 = EXP2F(ea * x0 * x0);  ub0 = EXP2F(eb * y0 * y0);
      ua1 = EXP2F(ea * x1 * x1);  ub1 = EXP2F(eb * y1 * y1);
      ua2 = EXP2F(ea * x2 * x2);  ub2 = EXP2F(eb * y2 * y2);
      ua3 = EXP2F(ea * x3 * x3);  ub3 = EXP2F(eb * y3 * y3);
      ua4 = EXP2F(ea * x4 * x4);  ub4 = EXP2F(eb * y4 * y4);
    }
    const float dAa =
        fmaf(ua0, P[7], fmaf(ua1, P[8], fmaf(ua2, P[9], fmaf(ua3, P[10], ua4 * P[11]))));
    const float dAb =
        fmaf(ub0, P[7], fmaf(ub1, P[8], fmaf(ub2, P[9], fmaf(ub3, P[10], ub4 * P[11]))));
    const float ta0 = fmaf(P[12], ua0, fmaf(P[17], ua1, fmaf(P[18], ua2, fmaf(P[19], ua3, P[20] * ua4))));
    const float tb0 = fmaf(P[12], ub0, fmaf(P[17], ub1, fmaf(P[18], ub2, fmaf(P[19], ub3, P[20] * ub4))));
    const float ta1 = fmaf(P[13], ua1, fmaf(P[21], ua2, fmaf(P[22], ua3, P[23] * ua4)));
    const float tb1 = fmaf(P[13], ub1, fmaf(P[21], ub2, fmaf(P[22], ub3, P[23] * ub4)));
    const float ta2 = fmaf(P[14], ua2, fmaf(P[24], ua3, P[25] * ua4));
    const float tb2 = fmaf(P[14], ub2, fmaf(P[24], ub3, P[25] * ub4));
    const float ta3 = fmaf(P[15], ua3, P[26] * ua4);
    const float tb3 = fmaf(P[15], ub3, P[26] * ub4);
    const float ta4 = P[16] * ua4;
    const float tb4 = P[16] * ub4;
    const float qa =
        fmaf(ua0, ta0, fmaf(ua1, ta1, fmaf(ua2, ta2, fmaf(ua3, ta3, ua4 * ta4))));
    const float qb =
        fmaf(ub0, tb0, fmaf(ub1, tb1, fmaf(ub2, tb2, fmaf(ub3, tb3, ub4 * tb4))));
    float meana = ca * dAa,  meanb = cb * dAb;
    float qkqa  = c2a * qa,  qkqb  = c2b * qb;

    // butterfly over c (low 3 lane bits)
    meana += __shfl_xor(meana, 1); meanb += __shfl_xor(meanb, 1);
    qkqa  += __shfl_xor(qkqa, 1);  qkqb  += __shfl_xor(qkqb, 1);
    meana += __shfl_xor(meana, 2); meanb += __shfl_xor(meanb, 2);
    qkqa  += __shfl_xor(qkqa, 2);  qkqb  += __shfl_xor(qkqb, 2);
    meana += __shfl_xor(meana, 4); meanb += __shfl_xor(meanb, 4);
    qkqa  += __shfl_xor(qkqa, 4);  qkqb  += __shfl_xor(qkqb, 4);
    outm[it] = make_float2(meana, meanb);
    outq[it] = make_float2(qkqa, qkqb);
  }

  if (c == 0) {
    float2* base = pmq + (size_t)(k * OC_N + o) * RTOT + rbase;
#pragma unroll
    for (int it = 0; it < 8; ++it) {
      const int r0 = it * 16;
      base[r0 + rh]     = make_float2(outm[it].x, outq[it].x);
      base[r0 + rh + 8] = make_float2(outm[it].y, outq[it].y);
    }
  }
}

// Coalesced reads of 9 partials; strided 4B out-stores (cheap).
__global__ __launch_bounds__(256) void gp_final_kernel(
    const float2* __restrict__ pmq, float* __restrict__ out) {
  const int j = blockIdx.x * 256 + threadIdx.x;   // 0..131071
  const int o = j >> 13;
  const int r = j & 8191;
  float m = 0.0f, q = 0.0f;
#pragma unroll
  for (int s = 0; s < 9; ++s) {
    const float2 v = pmq[(size_t)(s * OC_N + o) * RTOT + r];
    m += v.x;
    q += v.y;
  }
  const int i = r * OC_N + o;
  out[i] = m;
  out[OUT_HALF + i] = fmaxf(72.0f - q, 1e-6f);
}

extern "C" void kernel_launch(void* const* d_in, const int* in_sizes, int n_in,
                              void* d_out, int out_size, void* d_ws, size_t ws_size,
                              hipStream_t stream) {
  const float* xm = (const float*)d_in[0];   // x_mean [8,32,32,8]
  const float* xv = (const float*)d_in[1];   // x_var  [8,32,32,8]
  const float* z  = (const float*)d_in[2];   // [16,72,5]
  const float* h  = (const float*)d_in[3];   // [16,72,5]
  const float* rl = (const float*)d_in[4];   // [16,72]
  float* out = (float*)d_out;                // mean(131072) ++ var(131072)

  float* nr   = (float*)d_ws;                // 147456 B
  float2* pmq = (float2*)((char*)d_ws + NEU * NF * 4);  // 9*16*8192 float2

  gp_prep_kernel<<<dim3((NEU + 255) / 256), dim3(256), 0, stream>>>(z, h, rl, nr);

  dim3 grid(RTOT / 128, OC_N, 9);            // (64, 16, 9) = 9216 one-wave blocks
  gp_main_kernel<<<grid, dim3(64), 0, stream>>>(xm, xv, nr, pmq);

  gp_final_kernel<<<dim3(OUT_HALF / 256), dim3(256), 0, stream>>>(pmq, out);
}